// Round 5
// baseline (10255.344 us; speedup 1.0000x reference)
//
#include <hip/hip_runtime.h>
#include <hip/hip_fp16.h>

typedef _Float16 v8h __attribute__((ext_vector_type(8)));
typedef float    v4f __attribute__((ext_vector_type(4)));

// ---- workspace map (bytes) ----
#define OFF_KEYSH  0UL            // __half [128][128][256] (b,u,s)  = 8,388,608
#define OFF_WBF    8388608UL      // __half MFMA B-frags Wb: 32kt x 64nt x 64lane x 8 = 2,097,152
#define OFF_WCF    10485760UL     // __half MFMA B-frags Wc: 16kt x 64nt x 64lane x 8 = 1,048,576
#define OFF_W1T    11534336UL     // float  [128 u][512 e]           =   262,144
#define WS_CORE    11796480UL
#define OFF_ENCH   11796480UL     // __half [128][256][512]          = 33,554,432
#define WS_FULL    45350912UL

static __device__ __forceinline__ float fast_tanh(float x){
    float e = __expf(2.0f*x);
    return 1.0f - 2.0f*__builtin_amdgcn_rcpf(e + 1.0f);
}
static __device__ __forceinline__ float fast_sigm(float x){
    return __builtin_amdgcn_rcpf(1.0f + __expf(-x));
}

// ---------------- setup: MFMA B-fragment weight layouts, W1t, encH
// WbF half index = ((kt*64 + nt)*64 + lane)*8 + j
//   value = Wb[k][n], k = kt*32 + (lane>>4)*8 + j, n = nt*16 + (lane&15)
//   Wb rows: k<768 -> Wx1[k][n] (xk = [emb|ctx] order matches), else Wh1[k-768][n]
// WcF: kt 0..15, k<256 -> Wx2[k][n], else Wh2[k-256][n]  (xk2 = [h1|h2])
__global__ __launch_bounds__(256) void setup_kernel(
    const float* __restrict__ Wx1, const float* __restrict__ Wh1,
    const float* __restrict__ Wx2, const float* __restrict__ Wh2,
    const float* __restrict__ W1, const float* __restrict__ enc,
    __half* __restrict__ WbF, __half* __restrict__ WcF,
    float* __restrict__ W1t, __half* __restrict__ encH, long long total)
{
    long long id0 = (long long)blockIdx.x*blockDim.x + threadIdx.x;
    long long stride = (long long)gridDim.x*blockDim.x;
    for(long long id = id0; id < total; id += stride){
        if(id < 1048576LL){                         // WbF
            int j = (int)(id & 7), lane = (int)((id >> 3) & 63);
            int tile = (int)(id >> 9);
            int nt = tile & 63, kt = tile >> 6;
            int n = nt*16 + (lane & 15);
            int k = kt*32 + (lane >> 4)*8 + j;
            float v = (k < 768) ? Wx1[k*1024 + n] : Wh1[(k-768)*1024 + n];
            WbF[id] = __float2half(v);
        } else if(id < 1572864LL){                  // WcF
            long long i2 = id - 1048576LL;
            int j = (int)(i2 & 7), lane = (int)((i2 >> 3) & 63);
            int tile = (int)(i2 >> 9);
            int nt = tile & 63, kt = tile >> 6;
            int n = nt*16 + (lane & 15);
            int k = kt*32 + (lane >> 4)*8 + j;
            float v = (k < 256) ? Wx2[k*1024 + n] : Wh2[(k-256)*1024 + n];
            WcF[i2] = __float2half(v);
        } else if(id < 1638400LL){                  // W1t[u][e]
            long long i3 = id - 1572864LL;
            int u = (int)(i3 >> 9), e = (int)(i3 & 511);
            W1t[i3] = W1[e*128 + u];
        } else {                                    // encH
            long long i6 = id - 1638400LL;
            encH[i6] = __float2half(enc[i6]);
        }
    }
}

// ---------------- keys = enc @ W1 + b1, transposed fp16 keysH[b][u][s]
__global__ __launch_bounds__(256) void keys_kernel(
    const float* __restrict__ enc, const float* __restrict__ W1t,
    const float* __restrict__ b1, __half* __restrict__ keysH)
{
    const int bb = blockIdx.x;            // 1024 blocks
    const int b  = bb >> 3, sq = bb & 7;
    const int tid = threadIdx.x;
    const int u = tid & 127, sh = tid >> 7;
    const int s0 = sq*32 + sh*16;
    float acc[16];
    #pragma unroll
    for(int i = 0; i < 16; ++i) acc[i] = 0.0f;
    const float* wp = W1t + (size_t)u*512;
    const float* xp = enc + (size_t)(b*256 + s0)*512;
    for(int e = 0; e < 512; e += 4){
        float4 wv = *(const float4*)(wp + e);
        #pragma unroll
        for(int i = 0; i < 16; ++i){
            float4 xv = *(const float4*)(xp + (size_t)i*512 + e);
            acc[i] += wv.x*xv.x + wv.y*xv.y + wv.z*xv.z + wv.w*xv.w;
        }
    }
    const float bu = b1[u];
    __half* op = keysH + (size_t)(b*128 + u)*256 + s0;
    #pragma unroll
    for(int i = 0; i < 16; ++i) op[i] = __float2half(acc[i] + bu);
}

// ---------------- zero-sync decoder: 128 blocks x 1024 threads, block = batch.
// All state (h1,h2,c1,c2) block-local; LSTM weights streamed from L2 each step
// as MFMA B-fragments; x-vector broadcast to all 16 A rows (all C rows equal,
// read row 0). No grid barriers, no cross-block atomics anywhere.
__global__ __launch_bounds__(1024) void decoder_solo(
    const float* __restrict__ xdec, const float* __restrict__ embW, const float* __restrict__ embb,
    const float* __restrict__ W2, const float* __restrict__ b2,
    const float* __restrict__ V, const float* __restrict__ bVp,
    const float* __restrict__ Wo, const float* __restrict__ bop,
    const float* __restrict__ bl1, const float* __restrict__ bl2,
    const float* __restrict__ h1_in, const float* __restrict__ c1_in,
    const float* __restrict__ h2_in, const float* __restrict__ c2_in,
    const float* __restrict__ enc, const __half* __restrict__ encH,
    const __half* __restrict__ keysH,
    const __half* __restrict__ WbF, const __half* __restrict__ WcF,
    float* __restrict__ out, int useEncH)
{
    const int tid  = threadIdx.x;
    const int ab   = blockIdx.x;            // batch owned by this block
    const int w    = tid >> 6;              // wave 0..15
    const int lane = tid & 63;
    const int kg   = lane >> 4;

    __shared__ __align__(16) _Float16 xk[1024];   // [emb(256)|ctx(512)|h1(256)]
    __shared__ __align__(16) _Float16 xk2[512];   // [h1|h2]
    __shared__ __align__(16) float zs[1024];
    __shared__ float h2s[256];
    __shared__ __align__(16) float qp[8][128];
    __shared__ float qv[128];
    __shared__ __align__(16) float sp[4][256];
    __shared__ float at[256];
    __shared__ __align__(16) float ctxp[2][512];
    __shared__ float red[16];
    __shared__ float Vs[128];

    // ---- per-thread preloads (persist all 48 steps) ----
    float b2r = 0.0f;
    if(tid < 128){ Vs[tid] = V[tid]; b2r = b2[tid]; }
    float ew=0,eb=0,Wos=0;
    float bi1=0,bf1=0,bg1=0,bo1=0,bi2=0,bf2=0,bg2=0,bo2=0;
    float c1r=0.0f, c2r=0.0f;
    if(tid < 256){
        ew = embW[tid]; eb = embb[tid]; Wos = Wo[tid];
        bi1 = bl1[tid]; bf1 = bl1[256+tid]; bg1 = bl1[512+tid]; bo1 = bl1[768+tid];
        bi2 = bl2[tid]; bf2 = bl2[256+tid]; bg2 = bl2[512+tid]; bo2 = bl2[768+tid];
        c1r = c1_in[ab*256 + tid];
        c2r = c2_in[ab*256 + tid];
        h2s[tid] = h2_in[ab*256 + tid];
        xk[768 + tid] = (_Float16)h1_in[ab*256 + tid];
    }
    const float bVv = bVp[0], bov = bop[0];

    // per-wave streaming bases: byte addr(kt,i) = base + kt*65536 + i*1024
    const char* wbB = (const char*)WbF + (((size_t)(4*w)*64 + lane) << 4);
    const char* wcB = (const char*)WcF + (((size_t)(4*w)*64 + lane) << 4);
    __syncthreads();

    for(int t = 0; t < 48; ++t){
        // ---- q partials: 8 k-groups x 128 u ----
        {
            const int u = tid & 127, kq8 = tid >> 7, k0 = kq8*32;
            float a = 0.0f;
            #pragma unroll 8
            for(int k = k0; k < k0 + 32; ++k) a += h2s[k]*W2[k*128 + u];
            qp[kq8][u] = a;
        }
        __syncthreads();
        if(tid < 128){
            float a = b2r;
            #pragma unroll
            for(int j = 0; j < 8; ++j) a += qp[j][tid];
            qv[tid] = a;
        }
        __syncthreads();
        // ---- score partials: 4 u-quarters x 256 s ----
        {
            const int s = tid & 255, uq = tid >> 8;
            const __half* kp = keysH + ((size_t)(ab*128 + uq*32))*256 + s;
            float a = 0.0f;
            #pragma unroll 8
            for(int ui = 0; ui < 32; ++ui)
                a += fast_tanh(__half2float(kp[(size_t)ui*256]) + qv[uq*32 + ui]) * Vs[uq*32 + ui];
            sp[uq][s] = a;
        }
        __syncthreads();
        // ---- softmax over 256 (max-pass kept, all-LDS) ----
        float sc = 0.0f, pexp = 0.0f;
        if(tid < 256){
            sc = sp[0][tid] + sp[1][tid] + sp[2][tid] + sp[3][tid] + bVv;
            float mx = sc;
            #pragma unroll
            for(int off = 32; off >= 1; off >>= 1) mx = fmaxf(mx, __shfl_xor(mx, off));
            if(lane == 0) red[w] = mx;
        }
        __syncthreads();
        if(tid < 256){
            float mx = fmaxf(fmaxf(red[0], red[1]), fmaxf(red[2], red[3]));
            pexp = __expf(sc - mx);
            float su = pexp;
            #pragma unroll
            for(int off = 32; off >= 1; off >>= 1) su += __shfl_xor(su, off);
            if(lane == 0) red[4 + w] = su;
        }
        __syncthreads();
        if(tid < 256) at[tid] = pexp / (red[4] + red[5] + red[6] + red[7]);
        __syncthreads();
        // ---- ctx partials: 2 s-halves x 512 e ----
        {
            const int e = tid & 511, s2 = tid >> 9;
            float a = 0.0f;
            if(useEncH){
                const __half* ep = encH + ((size_t)(ab*256 + s2*128))*512 + e;
                #pragma unroll 8
                for(int si = 0; si < 128; ++si) a += at[s2*128 + si]*__half2float(ep[(size_t)si*512]);
            } else {
                const float* ep = enc + ((size_t)(ab*256 + s2*128))*512 + e;
                #pragma unroll 8
                for(int si = 0; si < 128; ++si) a += at[s2*128 + si]*ep[(size_t)si*512];
            }
            ctxp[s2][e] = a;
        }
        __syncthreads();
        // ---- xk build: emb | ctx  (h1 slot written by prev pointwise1) ----
        if(tid < 256){
            float x = xdec[ab*48 + t];
            xk[tid] = (_Float16)fmaxf(x*ew + eb, 0.0f);
        } else if(tid < 768){
            xk[tid] = (_Float16)(ctxp[0][tid-256] + ctxp[1][tid-256]);
        }
        __syncthreads();
        // ---- GEMV1 via MFMA: z[1024] = xk(1024) . Wb ; wave w owns gates 64w..64w+63
        {
            v4f a0 = {0,0,0,0}, a1 = a0, a2 = a0, a3 = a0;
            uint4 p0 = *(const uint4*)(wbB);
            uint4 p1 = *(const uint4*)(wbB + 1024);
            uint4 p2 = *(const uint4*)(wbB + 2048);
            uint4 p3 = *(const uint4*)(wbB + 3072);
            const _Float16* xp = &xk[kg*8];
            for(int kt = 0; kt < 31; ++kt){
                const char* nx = wbB + (size_t)(kt+1)*65536;
                uint4 n0 = *(const uint4*)(nx);
                uint4 n1 = *(const uint4*)(nx + 1024);
                uint4 n2 = *(const uint4*)(nx + 2048);
                uint4 n3 = *(const uint4*)(nx + 3072);
                v8h af = *(const v8h*)(xp + kt*32);
                a0 = __builtin_amdgcn_mfma_f32_16x16x32_f16(af, __builtin_bit_cast(v8h, p0), a0, 0, 0, 0);
                a1 = __builtin_amdgcn_mfma_f32_16x16x32_f16(af, __builtin_bit_cast(v8h, p1), a1, 0, 0, 0);
                a2 = __builtin_amdgcn_mfma_f32_16x16x32_f16(af, __builtin_bit_cast(v8h, p2), a2, 0, 0, 0);
                a3 = __builtin_amdgcn_mfma_f32_16x16x32_f16(af, __builtin_bit_cast(v8h, p3), a3, 0, 0, 0);
                p0 = n0; p1 = n1; p2 = n2; p3 = n3;
            }
            v8h af = *(const v8h*)(xp + 31*32);
            a0 = __builtin_amdgcn_mfma_f32_16x16x32_f16(af, __builtin_bit_cast(v8h, p0), a0, 0, 0, 0);
            a1 = __builtin_amdgcn_mfma_f32_16x16x32_f16(af, __builtin_bit_cast(v8h, p1), a1, 0, 0, 0);
            a2 = __builtin_amdgcn_mfma_f32_16x16x32_f16(af, __builtin_bit_cast(v8h, p2), a2, 0, 0, 0);
            a3 = __builtin_amdgcn_mfma_f32_16x16x32_f16(af, __builtin_bit_cast(v8h, p3), a3, 0, 0, 0);
            if(lane < 16){
                zs[w*64      + lane] = a0[0];
                zs[w*64 + 16 + lane] = a1[0];
                zs[w*64 + 32 + lane] = a2[0];
                zs[w*64 + 48 + lane] = a3[0];
            }
        }
        __syncthreads();
        // ---- pointwise LSTM1 ----
        if(tid < 256){
            float zi = zs[tid], zf = zs[256+tid], zg = zs[512+tid], zo = zs[768+tid];
            float cn = fast_sigm(zf + bf1)*c1r + fast_sigm(zi + bi1)*fast_tanh(zg + bg1);
            c1r = cn;
            float hn = fast_sigm(zo + bo1)*fast_tanh(cn);
            _Float16 hh = (_Float16)hn;
            xk[768 + tid] = hh;                    // next step's GEMV1 K-tail
            xk2[tid] = hh;                         // LSTM2 K first half
            xk2[256 + tid] = (_Float16)h2s[tid];   // h2(t-1)
        }
        __syncthreads();
        // ---- GEMV2 via MFMA: z[1024] = xk2(512) . Wc ----
        {
            v4f a0 = {0,0,0,0}, a1 = a0, a2 = a0, a3 = a0;
            uint4 p0 = *(const uint4*)(wcB);
            uint4 p1 = *(const uint4*)(wcB + 1024);
            uint4 p2 = *(const uint4*)(wcB + 2048);
            uint4 p3 = *(const uint4*)(wcB + 3072);
            const _Float16* xp = &xk2[kg*8];
            for(int kt = 0; kt < 15; ++kt){
                const char* nx = wcB + (size_t)(kt+1)*65536;
                uint4 n0 = *(const uint4*)(nx);
                uint4 n1 = *(const uint4*)(nx + 1024);
                uint4 n2 = *(const uint4*)(nx + 2048);
                uint4 n3 = *(const uint4*)(nx + 3072);
                v8h af = *(const v8h*)(xp + kt*32);
                a0 = __builtin_amdgcn_mfma_f32_16x16x32_f16(af, __builtin_bit_cast(v8h, p0), a0, 0, 0, 0);
                a1 = __builtin_amdgcn_mfma_f32_16x16x32_f16(af, __builtin_bit_cast(v8h, p1), a1, 0, 0, 0);
                a2 = __builtin_amdgcn_mfma_f32_16x16x32_f16(af, __builtin_bit_cast(v8h, p2), a2, 0, 0, 0);
                a3 = __builtin_amdgcn_mfma_f32_16x16x32_f16(af, __builtin_bit_cast(v8h, p3), a3, 0, 0, 0);
                p0 = n0; p1 = n1; p2 = n2; p3 = n3;
            }
            v8h af = *(const v8h*)(xp + 15*32);
            a0 = __builtin_amdgcn_mfma_f32_16x16x32_f16(af, __builtin_bit_cast(v8h, p0), a0, 0, 0, 0);
            a1 = __builtin_amdgcn_mfma_f32_16x16x32_f16(af, __builtin_bit_cast(v8h, p1), a1, 0, 0, 0);
            a2 = __builtin_amdgcn_mfma_f32_16x16x32_f16(af, __builtin_bit_cast(v8h, p2), a2, 0, 0, 0);
            a3 = __builtin_amdgcn_mfma_f32_16x16x32_f16(af, __builtin_bit_cast(v8h, p3), a3, 0, 0, 0);
            if(lane < 16){
                zs[w*64      + lane] = a0[0];
                zs[w*64 + 16 + lane] = a1[0];
                zs[w*64 + 32 + lane] = a2[0];
                zs[w*64 + 48 + lane] = a3[0];
            }
        }
        __syncthreads();
        // ---- pointwise LSTM2 + fused pred ----
        if(tid < 256){
            float zi = zs[tid], zf = zs[256+tid], zg = zs[512+tid], zo = zs[768+tid];
            float cn = fast_sigm(zf + bf2)*c2r + fast_sigm(zi + bi2)*fast_tanh(zg + bg2);
            c2r = cn;
            float hn = fast_sigm(zo + bo2)*fast_tanh(cn);
            h2s[tid] = hn;
            float pv = hn*Wos;
            #pragma unroll
            for(int off = 32; off >= 1; off >>= 1) pv += __shfl_xor(pv, off);
            if(lane == 0) red[8 + w] = pv;
        }
        __syncthreads();
        if(tid == 0) out[ab*48 + t] = red[8] + red[9] + red[10] + red[11] + bov;
    }
}

extern "C" void kernel_launch(void* const* d_in, const int* in_sizes, int n_in,
                              void* d_out, int out_size, void* d_ws, size_t ws_size,
                              hipStream_t stream)
{
    const float* xdec = (const float*)d_in[0];
    const float* h1_in= (const float*)d_in[1];
    const float* c1_in= (const float*)d_in[2];
    const float* h2_in= (const float*)d_in[3];
    const float* c2_in= (const float*)d_in[4];
    const float* enc  = (const float*)d_in[5];
    const float* embW = (const float*)d_in[6];
    const float* embb = (const float*)d_in[7];
    const float* W1   = (const float*)d_in[8];
    const float* b1   = (const float*)d_in[9];
    const float* W2   = (const float*)d_in[10];
    const float* b2   = (const float*)d_in[11];
    const float* V    = (const float*)d_in[12];
    const float* bV   = (const float*)d_in[13];
    const float* Wx1  = (const float*)d_in[14];
    const float* Wh1  = (const float*)d_in[15];
    const float* bl1  = (const float*)d_in[16];
    const float* Wx2  = (const float*)d_in[17];
    const float* Wh2  = (const float*)d_in[18];
    const float* bl2  = (const float*)d_in[19];
    const float* Wo   = (const float*)d_in[20];
    const float* bo   = (const float*)d_in[21];

    if(ws_size < WS_CORE) return;

    char* ws = (char*)d_ws;
    __half* keysH = (__half*)(ws + OFF_KEYSH);
    __half* WbF   = (__half*)(ws + OFF_WBF);
    __half* WcF   = (__half*)(ws + OFF_WCF);
    float*  W1t   = (float*) (ws + OFF_W1T);
    __half* encH  = (__half*)(ws + OFF_ENCH);

    const int useEncH = (ws_size >= WS_FULL) ? 1 : 0;
    const long long total = useEncH ? 18415616LL : 1638400LL;

    hipLaunchKernelGGL(setup_kernel, dim3(4096), dim3(256), 0, stream,
        Wx1, Wh1, Wx2, Wh2, W1, enc, WbF, WcF, W1t, encH, total);

    hipLaunchKernelGGL(keys_kernel, dim3(1024), dim3(256), 0, stream,
        enc, W1t, b1, keysH);

    hipLaunchKernelGGL(decoder_solo, dim3(128), dim3(1024), 0, stream,
        xdec, embW, embb, W2, b2, V, bV, Wo, bo, bl1, bl2,
        h1_in, c1_in, h2_in, c2_in, enc, encH, keysH, WbF, WcF,
        (float*)d_out, useEncH);
}

// Round 7
// 2153.204 us; speedup vs baseline: 4.7628x; 4.7628x over previous
//
#include <hip/hip_runtime.h>
#include <hip/hip_fp16.h>

#define AGENT __HIP_MEMORY_SCOPE_AGENT

typedef _Float16 v8h __attribute__((ext_vector_type(8)));
typedef float    v4f __attribute__((ext_vector_type(4)));
typedef unsigned long long u64;

// ---- workspace map (bytes) ----
#define OFF_KEYSH  0UL            // __half [128][128][256] (b,u,s)   = 8,388,608
#define OFF_WBF    8388608UL      // __half Wb B-frags, 4u+g perm: 32kt x 64nt x 64lane x 8 = 2,097,152
#define OFF_WCF    10485760UL     // __half Wc B-frags, 4u+g perm: 16kt x 64nt x 64lane x 8 = 1,048,576
#define OFF_W1T    11534336UL     // float [128 u][512 e]             =   262,144
#define OFF_CTXU   11796480UL     // float [128 b][2 half][512 e]     =   524,288
#define OFF_SU     12320768UL     // float [128 b][2 half]            =     1,024
#define OFF_H1     12321792UL     // uint  [2][128][128]              =   131,072
#define OFF_H2     12452864UL     // uint  [2][128][128]              =   131,072
#define OFF_CNT    12583936UL     // int[512]: [0..143] masters, [256+16j] subs = 2,048
#define WS_CORE    12585984UL
#define OFF_ENCH   12585984UL     // __half [128][256][512]           = 33,554,432
#define WS_FULL    46140416UL

static __device__ __forceinline__ float fast_tanh(float x){
    float e = __expf(2.0f*x);
    return 1.0f - 2.0f*__builtin_amdgcn_rcpf(e + 1.0f);
}
static __device__ __forceinline__ float fast_sigm(float x){
    return __builtin_amdgcn_rcpf(1.0f + __expf(-x));
}

// Hierarchical grid barrier over 256 blocks (round-4 proven mechanism, widened):
// 8 sub-counters x 32 blocks on distinct 64-B lines; combiner (old==31) resets
// its sub-line then bumps the per-phase master; all poll the single master
// line (<8). s_waitcnt(0) drains relaxed agent stores pre-arrival.
static __device__ __forceinline__ void gbar(int* cnt, int idx){
    __builtin_amdgcn_s_waitcnt(0);
    __syncthreads();
    if(threadIdx.x == 0){
        int* sub = &cnt[256 + ((blockIdx.x >> 5) << 4)];
        int old = __hip_atomic_fetch_add(sub, 1, __ATOMIC_RELAXED, AGENT);
        if(old == 31){
            __hip_atomic_store(sub, 0, __ATOMIC_RELAXED, AGENT);
            __builtin_amdgcn_s_waitcnt(0);
            __hip_atomic_fetch_add(&cnt[idx], 1, __ATOMIC_RELAXED, AGENT);
        }
        while(__hip_atomic_load(&cnt[idx], __ATOMIC_RELAXED, AGENT) < 8)
            __builtin_amdgcn_s_sleep(1);
    }
    __syncthreads();
}

// ---------------- setup: permuted MFMA B-frag weights, W1t, state packing, counters, encH
// WbF half idx = ((kt*64 + nt)*64 + lane)*8 + j ; c = nt*16 + (lane&15) (4u+g space)
//   n_raw = (c&3)*256 + (c>>2) ; k = kt*32 + (lane>>4)*8 + j
//   k<768 -> Wx1[k][n_raw] ([emb|ctx] rows), else Wh1[k-768][n_raw]
// WcF: kt 0..15 ; k<256 -> Wx2[k][n_raw], else Wh2[k-256][n_raw]  ([h1|h2])
__global__ __launch_bounds__(256) void setup_kernel(
    const float* __restrict__ Wx1, const float* __restrict__ Wh1,
    const float* __restrict__ Wx2, const float* __restrict__ Wh2,
    const float* __restrict__ W1,
    const float* __restrict__ h1_in, const float* __restrict__ h2_in,
    const float* __restrict__ enc,
    __half* __restrict__ WbF, __half* __restrict__ WcF, float* __restrict__ W1t,
    unsigned int* __restrict__ h1d, unsigned int* __restrict__ h2d,
    int* __restrict__ cnt, __half* __restrict__ encH, long long total)
{
    long long id0 = (long long)blockIdx.x*blockDim.x + threadIdx.x;
    long long stride = (long long)gridDim.x*blockDim.x;
    for(long long id = id0; id < total; id += stride){
        if(id < 1048576LL){                         // WbF
            int j = (int)(id & 7), lane = (int)((id >> 3) & 63);
            int tile = (int)(id >> 9);
            int nt = tile & 63, kt = tile >> 6;
            int c = nt*16 + (lane & 15);
            int n = (c & 3)*256 + (c >> 2);
            int k = kt*32 + (lane >> 4)*8 + j;
            float v = (k < 768) ? Wx1[k*1024 + n] : Wh1[(k-768)*1024 + n];
            WbF[id] = __float2half(v);
        } else if(id < 1572864LL){                  // WcF
            long long i2 = id - 1048576LL;
            int j = (int)(i2 & 7), lane = (int)((i2 >> 3) & 63);
            int tile = (int)(i2 >> 9);
            int nt = tile & 63, kt = tile >> 6;
            int c = nt*16 + (lane & 15);
            int n = (c & 3)*256 + (c >> 2);
            int k = kt*32 + (lane >> 4)*8 + j;
            float v = (k < 256) ? Wx2[k*1024 + n] : Wh2[(k-256)*1024 + n];
            WcF[i2] = __float2half(v);
        } else if(id < 1638400LL){                  // W1t[u][e]
            long long i3 = id - 1572864LL;
            int u = (int)(i3 >> 9), e = (int)(i3 & 511);
            W1t[i3] = W1[e*128 + u];
        } else if(id < 1654784LL){                  // h1d parity 0, packed fp16 pairs
            long long i4 = id - 1638400LL;
            int b = (int)(i4 >> 7), j = (int)(i4 & 127);
            __half2 p = __floats2half2_rn(h1_in[b*256 + 2*j], h1_in[b*256 + 2*j + 1]);
            h1d[i4] = __builtin_bit_cast(unsigned int, p);
        } else if(id < 1671168LL){                  // h2d parity 0
            long long i5 = id - 1654784LL;
            int b = (int)(i5 >> 7), j = (int)(i5 & 127);
            __half2 p = __floats2half2_rn(h2_in[b*256 + 2*j], h2_in[b*256 + 2*j + 1]);
            h2d[i5] = __builtin_bit_cast(unsigned int, p);
        } else if(id < 1671680LL){                  // cnt[512] zero
            cnt[(int)(id - 1671168LL)] = 0;
        } else {                                    // encH
            long long i6 = id - 1671680LL;
            encH[i6] = __float2half(enc[i6]);
        }
    }
}

// ---------------- keys = enc @ W1 + b1, transposed fp16 keysH[b][u][s]
__global__ __launch_bounds__(256) void keys_kernel(
    const float* __restrict__ enc, const float* __restrict__ W1t,
    const float* __restrict__ b1, __half* __restrict__ keysH)
{
    const int bb = blockIdx.x;            // 1024 blocks
    const int b  = bb >> 3, sq = bb & 7;
    const int tid = threadIdx.x;
    const int u = tid & 127, sh = tid >> 7;
    const int s0 = sq*32 + sh*16;
    float acc[16];
    #pragma unroll
    for(int i = 0; i < 16; ++i) acc[i] = 0.0f;
    const float* wp = W1t + (size_t)u*512;
    const float* xp = enc + (size_t)(b*256 + s0)*512;
    for(int e = 0; e < 512; e += 4){
        float4 wv = *(const float4*)(wp + e);
        #pragma unroll
        for(int i = 0; i < 16; ++i){
            float4 xv = *(const float4*)(xp + (size_t)i*512 + e);
            acc[i] += wv.x*xv.x + wv.y*xv.y + wv.z*xv.z + wv.w*xv.w;
        }
    }
    const float bu = b1[u];
    __half* op = keysH + (size_t)(b*128 + u)*256 + s0;
    #pragma unroll
    for(int i = 0; i < 16; ++i) op[i] = __float2half(acc[i] + bu);
}

// ---------------- persistent decoder: 256 blocks x 1024 threads (~1/CU)
// Attention: pair (ab = bid>>1) splits s in halves (sh = bid&1); deferred
// softmax normalization (no max pass; unnormalized ctx partials + partial
// sums via MALL). enc read from L2/L3 (proven r0-r4 pattern; ~29KB LDS so
// co-residency of all 256 blocks is guaranteed under any packing).
// LSTM: NT = bid>>2 owns gate-cols 16NT.. (4u+g perm); Hq = bid&3 owns batch
// rows 32Hq..; two 16-row tiles computed by parallel 8-wave groups (8-way
// K-split each). Weights register-resident as B-frags. 3 barriers/step.
__global__ __launch_bounds__(1024) void decoder_v6(
    const float* __restrict__ xdec, const float* __restrict__ embW, const float* __restrict__ embb,
    const float* __restrict__ W2, const float* __restrict__ b2,
    const float* __restrict__ V, const float* __restrict__ bVp,
    const float* __restrict__ Wo, const float* __restrict__ bop,
    const float* __restrict__ bl1, const float* __restrict__ bl2,
    const float* __restrict__ c1_in, const float* __restrict__ c2_in,
    const float* __restrict__ enc, const __half* __restrict__ encH,
    const __half* __restrict__ keysH,
    const __half* __restrict__ WbF, const __half* __restrict__ WcF,
    float* CTXU, float* SU,
    unsigned int* h1d, unsigned int* h2d,
    int* cnt, float* __restrict__ out, int useEncH)
{
    const int tid  = threadIdx.x;
    const int bid  = blockIdx.x;
    const int ab   = bid >> 1, sh = bid & 1;   // attention half-owner
    const int NT   = bid >> 2, Hq = bid & 3;   // LSTM tile
    const int w    = tid >> 6;                 // wave 0..15
    const int lane = tid & 63;
    const int cl   = lane & 15;                // MFMA A-row / C-col
    const int kg   = lane >> 4;                // MFMA k-quad
    const int g    = w >> 3;                   // row-tile group 0..1
    const int wk   = w & 7;                    // K-split index 0..7
    const int uu   = lane >> 4;                // pointwise unit-local
    const int bl   = lane & 15;                // pointwise batch-local

    __shared__ __align__(16) float zb[2][8][16][20]; // 20480
    __shared__ float spb[8][128];                  // 4096 (q partials, then score partials)
    __shared__ float qv[128];                      // 512
    __shared__ float pexpA[128];                   // 512
    __shared__ float h2s[256];                     // 1024
    __shared__ float red[16];                      // 64
    __shared__ float Vs[128];                      // 512
    __shared__ float embWs[256];                   // 1024
    __shared__ float embbs[256];                   // 1024  -> total ~29.2 KB

    // ---- LDS / register preloads ----
    float b2r = 0.0f; float2 wo2 = make_float2(0.f, 0.f);
    if(tid < 128){
        Vs[tid] = V[tid]; b2r = b2[tid];
        wo2 = make_float2(Wo[2*tid], Wo[2*tid+1]);
    }
    if(tid < 256){ embWs[tid] = embW[tid]; embbs[tid] = embb[tid]; }
    const float bVv = bVp[0], bov = bop[0];

    // ---- register-resident weight B-frags ----
    uint4 wfb[4];
    #pragma unroll
    for(int i = 0; i < 4; ++i){
        int kt = wk*4 + i;
        wfb[i] = *(const uint4*)((const char*)WbF + (((size_t)(kt*64 + NT)*64 + lane) << 4));
    }
    uint4 wfc[2];
    #pragma unroll
    for(int i = 0; i < 2; ++i){
        int kt = wk*2 + i;
        wfc[i] = *(const uint4*)((const char*)WcF + (((size_t)(kt*64 + NT)*64 + lane) << 4));
    }

    // ---- reducer-wave cell state + gate biases (waves 0 and 8) ----
    const int ug = 4*NT + uu;
    float bi1=0,bf1=0,bg1=0,bo1=0,bi2=0,bf2=0,bg2=0,bo2=0;
    float c1r = 0.0f, c2r = 0.0f;
    if(wk == 0){
        bi1 = bl1[ug]; bf1 = bl1[256+ug]; bg1 = bl1[512+ug]; bo1 = bl1[768+ug];
        bi2 = bl2[ug]; bf2 = bl2[256+ug]; bg2 = bl2[512+ug]; bo2 = bl2[768+ug];
        const int bb0 = 32*Hq + 16*g + bl;
        c1r = c1_in[bb0*256 + ug];
        c2r = c2_in[bb0*256 + ug];
    }
    __syncthreads();

    for(int t = 0; t < 48; ++t){
        const int rpar = t & 1, wpar = rpar ^ 1;
        unsigned int* h1r = h1d + rpar*16384;
        unsigned int* h1w = h1d + wpar*16384;
        unsigned int* h2r = h2d + rpar*16384;
        unsigned int* h2w = h2d + wpar*16384;

        // ================= PHASE A : attention half + pred(t-1) =================
        if(tid < 128){
            unsigned int v = __hip_atomic_load(&h2r[ab*128 + tid], __ATOMIC_RELAXED, AGENT);
            float2 f = __half22float2(__builtin_bit_cast(__half2, v));
            h2s[2*tid] = f.x; h2s[2*tid+1] = f.y;
            float pv = f.x*wo2.x + f.y*wo2.y;
            #pragma unroll
            for(int off = 32; off >= 1; off >>= 1) pv += __shfl_xor(pv, off);
            if(lane == 0) red[8 + w] = pv;
        }
        __syncthreads();
        if(tid == 0 && t > 0 && sh == 0) out[ab*48 + (t-1)] = red[8] + red[9] + bov;
        // q partials: 8 k-groups x 128 u
        {
            const int u = tid & 127, kq = tid >> 7, k0 = kq*32;
            float a = 0.0f;
            #pragma unroll 8
            for(int k = k0; k < k0 + 32; ++k) a += h2s[k]*W2[k*128 + u];
            spb[kq][u] = a;
        }
        __syncthreads();
        if(tid < 128){
            float a = b2r;
            #pragma unroll
            for(int j = 0; j < 8; ++j) a += spb[j][tid];
            qv[tid] = a;
        }
        __syncthreads();
        // score partials over this block's s-half: 8 u-groups x 128 s
        {
            const int sl = tid & 127, uo = tid >> 7;
            const __half* kp = keysH + ((size_t)(ab*128 + uo*16))*256 + sh*128 + sl;
            float a = 0.0f;
            #pragma unroll 8
            for(int ui = 0; ui < 16; ++ui){
                const int u = uo*16 + ui;
                a += fast_tanh(__half2float(kp[(size_t)ui*256]) + qv[u]) * Vs[u];
            }
            spb[uo][sl] = a;
        }
        __syncthreads();
        // pexp (no max pass; |score| <= sum|V| ~ 28, fp32-safe) + partial sum
        if(tid < 128){
            float sc = bVv;
            #pragma unroll
            for(int j = 0; j < 8; ++j) sc += spb[j][tid];
            float p = __expf(sc);
            pexpA[tid] = p;
            float su = p;
            #pragma unroll
            for(int off = 32; off >= 1; off >>= 1) su += __shfl_xor(su, off);
            if(lane == 0) red[w] = su;
        }
        __syncthreads();
        if(tid == 0)
            __hip_atomic_store(&SU[ab*2 + sh], red[0] + red[1], __ATOMIC_RELAXED, AGENT);
        // unnormalized ctx partial: 512 threads over e, s-half from L2/L3
        if(tid < 512){
            float a = 0.0f;
            if(useEncH){
                const __half* ep = encH + ((size_t)(ab*256 + sh*128))*512 + tid;
                #pragma unroll 8
                for(int s = 0; s < 128; ++s) a += pexpA[s]*__half2float(ep[(size_t)s*512]);
            } else {
                const float* ep = enc + ((size_t)(ab*256 + sh*128))*512 + tid;
                #pragma unroll 8
                for(int s = 0; s < 128; ++s) a += pexpA[s]*ep[(size_t)s*512];
            }
            __hip_atomic_store(&CTXU[((size_t)ab*2 + sh)*512 + tid], a, __ATOMIC_RELAXED, AGENT);
        }
        gbar(cnt, 3*t + 0);

        // ================= PHASE B : LSTM1 (parallel row-tiles, 8-way K-split) =====
        {
            const int rowB = 32*Hq + 16*g + cl;
            uint4 af[4];
            if(wk < 2){            // emb region: rank-1, recompute from consts
                const float x = xdec[rowB*48 + t];
                #pragma unroll
                for(int i = 0; i < 4; ++i){
                    const int K = wk*128 + 32*i + kg*8;
                    v8h hv;
                    #pragma unroll
                    for(int j = 0; j < 8; ++j)
                        hv[j] = (_Float16)fmaxf(x*embWs[K+j] + embbs[K+j], 0.0f);
                    af[i] = __builtin_bit_cast(uint4, hv);
                }
            } else if(wk < 6){     // ctx region: combine halves, deferred normalize
                u64 sv = __hip_atomic_load((u64*)(SU + rowB*2), __ATOMIC_RELAXED, AGENT);
                float2 ss = __builtin_bit_cast(float2, sv);
                float rn = 1.0f/(ss.x + ss.y);
                u64* cp = (u64*)(CTXU + (size_t)rowB*1024);
                #pragma unroll
                for(int i = 0; i < 4; ++i){
                    const int e0 = (wk-2)*128 + 32*i + kg*8;
                    u64 a0 = __hip_atomic_load(cp + (e0>>1),       __ATOMIC_RELAXED, AGENT);
                    u64 a1 = __hip_atomic_load(cp + (e0>>1) + 1,   __ATOMIC_RELAXED, AGENT);
                    u64 a2 = __hip_atomic_load(cp + (e0>>1) + 2,   __ATOMIC_RELAXED, AGENT);
                    u64 a3 = __hip_atomic_load(cp + (e0>>1) + 3,   __ATOMIC_RELAXED, AGENT);
                    u64 b0 = __hip_atomic_load(cp + 256 + (e0>>1),     __ATOMIC_RELAXED, AGENT);
                    u64 b1 = __hip_atomic_load(cp + 256 + (e0>>1) + 1, __ATOMIC_RELAXED, AGENT);
                    u64 b2v= __hip_atomic_load(cp + 256 + (e0>>1) + 2, __ATOMIC_RELAXED, AGENT);
                    u64 b3 = __hip_atomic_load(cp + 256 + (e0>>1) + 3, __ATOMIC_RELAXED, AGENT);
                    float2 fa0 = __builtin_bit_cast(float2, a0), fb0 = __builtin_bit_cast(float2, b0);
                    float2 fa1 = __builtin_bit_cast(float2, a1), fb1 = __builtin_bit_cast(float2, b1);
                    float2 fa2 = __builtin_bit_cast(float2, a2), fb2 = __builtin_bit_cast(float2, b2v);
                    float2 fa3 = __builtin_bit_cast(float2, a3), fb3 = __builtin_bit_cast(float2, b3);
                    v8h hv;
                    hv[0] = (_Float16)((fa0.x+fb0.x)*rn); hv[1] = (_Float16)((fa0.y+fb0.y)*rn);
                    hv[2] = (_Float16)((fa1.x+fb1.x)*rn); hv[3] = (_Float16)((fa1.y+fb1.y)*rn);
                    hv[4] = (_Float16)((fa2.x+fb2.x)*rn); hv[5] = (_Float16)((fa2.y+fb2.y)*rn);
                    hv[6] = (_Float16)((fa3.x+fb3.x)*rn); hv[7] = (_Float16)((fa3.y+fb3.y)*rn);
                    af[i] = __builtin_bit_cast(uint4, hv);
                }
            } else {               // h1(t-1) region: packed fp16 pairs via MALL
                const u64* hp = (const u64*)h1r + (size_t)rowB*64;
                #pragma unroll
                for(int i = 0; i < 4; ++i){
                    const int K0 = (wk-6)*128 + 32*i + kg*8;
                    u64 q0 = __hip_atomic_load((u64*)hp + (K0>>2),     __ATOMIC_RELAXED, AGENT);
                    u64 q1 = __hip_atomic_load((u64*)hp + (K0>>2) + 1, __ATOMIC_RELAXED, AGENT);
                    af[i] = make_uint4((unsigned int)q0, (unsigned int)(q0>>32),
                                       (unsigned int)q1, (unsigned int)(q1>>32));
                }
            }
            v4f acc = {0.0f, 0.0f, 0.0f, 0.0f};
            #pragma unroll
            for(int i = 0; i < 4; ++i)
                acc = __builtin_amdgcn_mfma_f32_16x16x32_f16(
                        __builtin_bit_cast(v8h, af[i]), __builtin_bit_cast(v8h, wfb[i]), acc, 0, 0, 0);
            #pragma unroll
            for(int r = 0; r < 4; ++r) zb[g][wk][kg*4 + r][cl] = acc[r];
            __syncthreads();
            if(wk == 0){
                v4f z = {0.0f, 0.0f, 0.0f, 0.0f};
                #pragma unroll
                for(int q = 0; q < 8; ++q) z += *(const v4f*)&zb[g][q][bl][uu*4];
                float cn = fast_sigm(z.y + bf1)*c1r + fast_sigm(z.x + bi1)*fast_tanh(z.z + bg1);
                c1r = cn;
                float hn = fast_sigm(z.w + bo1)*fast_tanh(cn);
                float hp2 = __shfl_xor(hn, 16);
                if((uu & 1) == 0){
                    __half2 ph = __floats2half2_rn(hn, hp2);
                    int bb = 32*Hq + 16*g + bl;
                    __hip_atomic_store(&h1w[bb*128 + 2*NT + (uu >> 1)],
                                       __builtin_bit_cast(unsigned int, ph),
                                       __ATOMIC_RELAXED, AGENT);
                }
            }
        }
        gbar(cnt, 3*t + 1);

        // ================= PHASE C : LSTM2 (parallel row-tiles, 8-way K-split) =====
        {
            const int rowB = 32*Hq + 16*g + cl;
            uint4 af2[2];
            #pragma unroll
            for(int i = 0; i < 2; ++i){
                const int kt = wk*2 + i;
                const int K0 = kt*32 + kg*8;
                const u64* hp = (kt < 8) ? ((const u64*)h1w + (size_t)rowB*64 + (K0>>2))
                                         : ((const u64*)h2r + (size_t)rowB*64 + ((K0-256)>>2));
                u64 q0 = __hip_atomic_load((u64*)hp,     __ATOMIC_RELAXED, AGENT);
                u64 q1 = __hip_atomic_load((u64*)hp + 1, __ATOMIC_RELAXED, AGENT);
                af2[i] = make_uint4((unsigned int)q0, (unsigned int)(q0>>32),
                                    (unsigned int)q1, (unsigned int)(q1>>32));
            }
            v4f acc = {0.0f, 0.0f, 0.0f, 0.0f};
            #pragma unroll
            for(int i = 0; i < 2; ++i)
                acc = __builtin_amdgcn_mfma_f32_16x16x32_f16(
                        __builtin_bit_cast(v8h, af2[i]), __builtin_bit_cast(v8h, wfc[i]), acc, 0, 0, 0);
            #pragma unroll
            for(int r = 0; r < 4; ++r) zb[g][wk][kg*4 + r][cl] = acc[r];
            __syncthreads();
            if(wk == 0){
                v4f z = {0.0f, 0.0f, 0.0f, 0.0f};
                #pragma unroll
                for(int q = 0; q < 8; ++q) z += *(const v4f*)&zb[g][q][bl][uu*4];
                float cn = fast_sigm(z.y + bf2)*c2r + fast_sigm(z.x + bi2)*fast_tanh(z.z + bg2);
                c2r = cn;
                float hn = fast_sigm(z.w + bo2)*fast_tanh(cn);
                float hp2 = __shfl_xor(hn, 16);
                if((uu & 1) == 0){
                    __half2 ph = __floats2half2_rn(hn, hp2);
                    int bb = 32*Hq + 16*g + bl;
                    __hip_atomic_store(&h2w[bb*128 + 2*NT + (uu >> 1)],
                                       __builtin_bit_cast(unsigned int, ph),
                                       __ATOMIC_RELAXED, AGENT);
                }
            }
        }
        gbar(cnt, 3*t + 2);
    }

    // final pred (t=47): h2 at parity 0
    if((bid & 1) == 0){
        if(tid < 128){
            unsigned int v = __hip_atomic_load(&h2d[ab*128 + tid], __ATOMIC_RELAXED, AGENT);
            float2 f = __half22float2(__builtin_bit_cast(__half2, v));
            float pv = f.x*wo2.x + f.y*wo2.y;
            #pragma unroll
            for(int off = 32; off >= 1; off >>= 1) pv += __shfl_xor(pv, off);
            if(lane == 0) red[w] = pv;
        }
        __syncthreads();
        if(tid == 0) out[ab*48 + 47] = red[0] + red[1] + bov;
    }
}

extern "C" void kernel_launch(void* const* d_in, const int* in_sizes, int n_in,
                              void* d_out, int out_size, void* d_ws, size_t ws_size,
                              hipStream_t stream)
{
    const float* xdec = (const float*)d_in[0];
    const float* h1_in= (const float*)d_in[1];
    const float* c1_in= (const float*)d_in[2];
    const float* h2_in= (const float*)d_in[3];
    const float* c2_in= (const float*)d_in[4];
    const float* enc  = (const float*)d_in[5];
    const float* embW = (const float*)d_in[6];
    const float* embb = (const float*)d_in[7];
    const float* W1   = (const float*)d_in[8];
    const float* b1   = (const float*)d_in[9];
    const float* W2   = (const float*)d_in[10];
    const float* b2   = (const float*)d_in[11];
    const float* V    = (const float*)d_in[12];
    const float* bV   = (const float*)d_in[13];
    const float* Wx1  = (const float*)d_in[14];
    const float* Wh1  = (const float*)d_in[15];
    const float* bl1  = (const float*)d_in[16];
    const float* Wx2  = (const float*)d_in[17];
    const float* Wh2  = (const float*)d_in[18];
    const float* bl2  = (const float*)d_in[19];
    const float* Wo   = (const float*)d_in[20];
    const float* bo   = (const float*)d_in[21];

    if(ws_size < WS_CORE) return;

    char* ws = (char*)d_ws;
    __half* keysH = (__half*)(ws + OFF_KEYSH);
    __half* WbF   = (__half*)(ws + OFF_WBF);
    __half* WcF   = (__half*)(ws + OFF_WCF);
    float*  W1t   = (float*) (ws + OFF_W1T);
    float*  CTXU  = (float*) (ws + OFF_CTXU);
    float*  SU    = (float*) (ws + OFF_SU);
    unsigned int* h1d = (unsigned int*)(ws + OFF_H1);
    unsigned int* h2d = (unsigned int*)(ws + OFF_H2);
    int*    cnt   = (int*)   (ws + OFF_CNT);
    __half* encH  = (__half*)(ws + OFF_ENCH);

    const int useEncH = (ws_size >= WS_FULL) ? 1 : 0;
    const long long total = useEncH ? 18448896LL : 1671680LL;

    hipLaunchKernelGGL(setup_kernel, dim3(4096), dim3(256), 0, stream,
        Wx1, Wh1, Wx2, Wh2, W1, h1_in, h2_in, enc,
        WbF, WcF, W1t, h1d, h2d, cnt, encH, total);

    hipLaunchKernelGGL(keys_kernel, dim3(1024), dim3(256), 0, stream,
        enc, W1t, b1, keysH);

    hipLaunchKernelGGL(decoder_v6, dim3(256), dim3(1024), 0, stream,
        xdec, embW, embb, W2, b2, V, bV, Wo, bo, bl1, bl2,
        c1_in, c2_in, enc, encH, keysH, WbF, WcF, CTXU, SU,
        h1d, h2d, cnt, (float*)d_out, useEncH);
}